// Round 1
// baseline (328.965 us; speedup 1.0000x reference)
//
#include <hip/hip_runtime.h>
#include <cstdint>

// Problem sizes (fixed by reference)
#define S_    2048
#define DM    1024
#define DH    4096
#define NTOK  8192   // B*S = 4*2048
#define WELEM 4194304  // 4096*1024 elements in each weight matrix

typedef int v4i __attribute__((ext_vector_type(4)));

// ---------------------------------------------------------------------------
// Stage 1: per-block partial sums of |w| in fp64 (deterministic: fixed mapping)
// 1024 blocks x 4096 elements each.
__global__ __launch_bounds__(256) void absmean_partial(const float* __restrict__ w,
                                                       double* __restrict__ partial) {
    __shared__ double red[256];
    int base = blockIdx.x * 4096;
    double s = 0.0;
#pragma unroll
    for (int k = 0; k < 16; ++k) {
        float v = w[base + (k << 8) + threadIdx.x];
        s += (double)fabsf(v);
    }
    red[threadIdx.x] = s;
    __syncthreads();
    for (int off = 128; off > 0; off >>= 1) {
        if (threadIdx.x < off) red[threadIdx.x] += red[threadIdx.x + off];
        __syncthreads();
    }
    if (threadIdx.x == 0) partial[blockIdx.x] = red[0];
}

// Stage 2: deterministic tree-sum of the 1024 partials for each matrix,
// then compute scale = 1/clip(mean,1e-5) and dequant = 1/scale (both fp32,
// mirroring the reference's fp32 ops).
__global__ __launch_bounds__(256) void finalize_scales(const double* __restrict__ p1,
                                                       const double* __restrict__ p2,
                                                       float* __restrict__ sc) {
    __shared__ double red[1024];
#pragma unroll 1
    for (int m = 0; m < 2; ++m) {
        const double* p = (m == 0) ? p1 : p2;
        __syncthreads();
#pragma unroll
        for (int k = 0; k < 4; ++k) red[(k << 8) + threadIdx.x] = p[(k << 8) + threadIdx.x];
        __syncthreads();
        double s = red[threadIdx.x] + red[threadIdx.x + 256] +
                   red[threadIdx.x + 512] + red[threadIdx.x + 768];
        __syncthreads();
        red[threadIdx.x] = s;
        __syncthreads();
        for (int off = 128; off > 0; off >>= 1) {
            if (threadIdx.x < off) red[threadIdx.x] += red[threadIdx.x + off];
            __syncthreads();
        }
        if (threadIdx.x == 0) {
            double mean = red[0] / (double)WELEM;
            float mf = fmaxf((float)mean, 1e-5f);
            float scale = 1.0f / mf;        // reference: scale = 1/clip(mean)
            sc[2 * m]     = scale;
            sc[2 * m + 1] = 1.0f / scale;   // dequant unit, fp32 like reference
        }
    }
}

// Ternary-quantize a weight matrix: q = clip(rint(w*scale), -1, 1)
__global__ __launch_bounds__(256) void quant_w(const float4* __restrict__ w,
                                               char4* __restrict__ q,
                                               const float* __restrict__ sc, int slot) {
    float scale = sc[slot];
    int i = blockIdx.x * 256 + threadIdx.x;
    float4 v = w[i];
    char4 o;
    o.x = (signed char)(int)fminf(fmaxf(rintf(v.x * scale), -1.f), 1.f);
    o.y = (signed char)(int)fminf(fmaxf(rintf(v.y * scale), -1.f), 1.f);
    o.z = (signed char)(int)fminf(fmaxf(rintf(v.z * scale), -1.f), 1.f);
    o.w = (signed char)(int)fminf(fmaxf(rintf(v.w * scale), -1.f), 1.f);
    q[i] = o;
}

// Per-token int8 absmax quantization of x (row length DM=1024)
__global__ __launch_bounds__(256) void quant_x_kernel(const float* __restrict__ x,
                                                      int8_t* __restrict__ q,
                                                      float* __restrict__ dq) {
    __shared__ float red[256];
    int t = blockIdx.x;
    const float* row = x + (size_t)t * DM;
    float v[4];
    float mx = 0.f;
#pragma unroll
    for (int k = 0; k < 4; ++k) {
        v[k] = row[(k << 8) + threadIdx.x];
        mx = fmaxf(mx, fabsf(v[k]));
    }
    red[threadIdx.x] = mx;
    __syncthreads();
    for (int off = 128; off > 0; off >>= 1) {
        if (threadIdx.x < off) red[threadIdx.x] = fmaxf(red[threadIdx.x], red[threadIdx.x + off]);
        __syncthreads();
    }
    float scale = 127.0f / fmaxf(red[0], 1e-5f);
#pragma unroll
    for (int k = 0; k < 4; ++k) {
        float qq = fminf(fmaxf(rintf(v[k] * scale), -128.f), 127.f);
        q[(size_t)t * DM + (k << 8) + threadIdx.x] = (int8_t)(int)qq;
    }
    if (threadIdx.x == 0) dq[t] = 1.0f / scale;
}

// Fused depthwise conv3 (+bias) + SiLU + per-token int8 quant over DH=4096.
// One block per token; sequence padding is per-batch (S_=2048 divides tokens).
__global__ __launch_bounds__(256) void conv_silu_quant(const float* __restrict__ h,
                                                       const float* __restrict__ cw,
                                                       const float* __restrict__ cb,
                                                       int8_t* __restrict__ q,
                                                       float* __restrict__ dq) {
    __shared__ float red[256];
    int t = blockIdx.x;
    int s = t & (S_ - 1);
    const float* h0 = h + (size_t)t * DH;
    const float* hm = h0 - DH;
    const float* hp = h0 + DH;
    bool has_m = (s > 0), has_p = (s < S_ - 1);
    float v[16];
    float mx = 0.f;
#pragma unroll
    for (int k = 0; k < 16; ++k) {
        int c = (k << 8) + threadIdx.x;
        float a  = has_m ? hm[c] : 0.f;
        float b  = h0[c];
        float cc = has_p ? hp[c] : 0.f;
        float y = cw[c * 3] * a + cw[c * 3 + 1] * b + cw[c * 3 + 2] * cc + cb[c];
        float sg = 1.0f / (1.0f + expf(-y));
        v[k] = y * sg;
        mx = fmaxf(mx, fabsf(v[k]));
    }
    red[threadIdx.x] = mx;
    __syncthreads();
    for (int off = 128; off > 0; off >>= 1) {
        if (threadIdx.x < off) red[threadIdx.x] = fmaxf(red[threadIdx.x], red[threadIdx.x + off]);
        __syncthreads();
    }
    float scale = 127.0f / fmaxf(red[0], 1e-5f);
#pragma unroll
    for (int k = 0; k < 16; ++k) {
        int c = (k << 8) + threadIdx.x;
        float qq = fminf(fmaxf(rintf(v[k] * scale), -128.f), 127.f);
        q[(size_t)t * DH + c] = (int8_t)(int)qq;
    }
    if (threadIdx.x == 0) dq[t] = 1.0f / scale;
}

// int8 x ternary GEMM: C[m,n] = (sum_k A[m,k]*B[n,k]) * rowdq[m] * sc[slot]
// A: [M,K] int8 row-major, B: [N,K] int8 row-major (both K-contiguous).
// Block tile 128x128, 4 waves in 2x2, each wave 64x64 via 4x4 grid of
// mfma_i32_16x16x64_i8. LDS tiles stored in fragment order: per 16-row tile,
// offset(m,k16) = (k16*16 + m)*16 bytes, so each lane's ds_read_b128 at
// lane*16 is fully sequential (conflict-free).
__global__ __launch_bounds__(256) void gemm_i8(const int8_t* __restrict__ A,
                                               const int8_t* __restrict__ Bm,
                                               float* __restrict__ C,
                                               const float* __restrict__ rowdq,
                                               const float* __restrict__ sc, int slot,
                                               int N, int K) {
    __shared__ __align__(16) int8_t Alds[8192];
    __shared__ __align__(16) int8_t Blds[8192];
    const int tid  = threadIdx.x;
    const int lane = tid & 63;
    const int wave = tid >> 6;
    const int mbase = blockIdx.y << 7;
    const int nbase = blockIdx.x << 7;
    const int wm4 = (wave >> 1) << 2;  // wave's first m-tile (of 16 rows)
    const int wn4 = (wave & 1) << 2;   // wave's first n-tile

    v4i acc[4][4] = {};

    for (int k0 = 0; k0 < K; k0 += 64) {
        __syncthreads();
#pragma unroll
        for (int i = 0; i < 2; ++i) {
            int c = tid + (i << 8);       // chunk id in [0,512)
            int row = c >> 2;             // tile row 0..127
            int c4  = c & 3;              // which 16B chunk of the 64B row
            int ldsoff = ((row >> 4) << 10) + (((c4 << 4) + (row & 15)) << 4);
            const int4 va = *reinterpret_cast<const int4*>(
                A + (size_t)(mbase + row) * K + k0 + (c4 << 4));
            *reinterpret_cast<int4*>(Alds + ldsoff) = va;
            const int4 vb = *reinterpret_cast<const int4*>(
                Bm + (size_t)(nbase + row) * K + k0 + (c4 << 4));
            *reinterpret_cast<int4*>(Blds + ldsoff) = vb;
        }
        __syncthreads();
        v4i af[4], bf[4];
#pragma unroll
        for (int i = 0; i < 4; ++i)
            af[i] = *reinterpret_cast<const v4i*>(Alds + ((wm4 + i) << 10) + (lane << 4));
#pragma unroll
        for (int j = 0; j < 4; ++j)
            bf[j] = *reinterpret_cast<const v4i*>(Blds + ((wn4 + j) << 10) + (lane << 4));
#pragma unroll
        for (int i = 0; i < 4; ++i)
#pragma unroll
            for (int j = 0; j < 4; ++j)
                acc[i][j] = __builtin_amdgcn_mfma_i32_16x16x64_i8(af[i], bf[j], acc[i][j], 0, 0, 0);
    }

    const float wdq = sc[slot];
    const int quad = lane >> 4;
    const int col  = lane & 15;
#pragma unroll
    for (int i = 0; i < 4; ++i) {
#pragma unroll
        for (int r = 0; r < 4; ++r) {
            int m = mbase + ((wm4 + i) << 4) + (quad << 2) + r;  // C/D: row=(lane>>4)*4+reg
            float rs = rowdq[m] * wdq;
#pragma unroll
            for (int j = 0; j < 4; ++j) {
                int n = nbase + ((wn4 + j) << 4) + col;          // C/D: col=lane&15
                C[(size_t)m * N + n] = (float)acc[i][j][r] * rs;
            }
        }
    }
}

// ---------------------------------------------------------------------------
extern "C" void kernel_launch(void* const* d_in, const int* in_sizes, int n_in,
                              void* d_out, int out_size, void* d_ws, size_t ws_size,
                              hipStream_t stream) {
    const float* x  = (const float*)d_in[0];  // [4,2048,1024]
    const float* w1 = (const float*)d_in[1];  // [4096,1024]
    const float* cw = (const float*)d_in[2];  // [4096,1,3]
    const float* cb = (const float*)d_in[3];  // [4096]
    const float* w2 = (const float*)d_in[4];  // [1024,4096]
    float* out = (float*)d_out;               // [4,2048,1024]
    char* ws = (char*)d_ws;

    // Workspace layout (all offsets 16B-aligned); total ~184.7 MB
    double* part1 = (double*)(ws + 0);          // 1024 doubles
    double* part2 = (double*)(ws + 8192);       // 1024 doubles
    float*  sc    = (float*)(ws + 16384);       // {scale_w1, dq_w1, scale_w2, dq_w2}
    float*  dqx   = (float*)(ws + 16640);       // 8192 floats
    float*  dqh   = (float*)(ws + 49408);       // 8192 floats
    int8_t* qw1   = (int8_t*)(ws + 82176);      // 4 MB
    int8_t* qw2   = (int8_t*)(ws + 4276480);    // 4 MB
    int8_t* qx    = (int8_t*)(ws + 8470784);    // 8 MB
    int8_t* qh    = (int8_t*)(ws + 16859392);   // 32 MB
    float*  h     = (float*)(ws + 50413824);    // 128 MB

    absmean_partial<<<1024, 256, 0, stream>>>(w1, part1);
    absmean_partial<<<1024, 256, 0, stream>>>(w2, part2);
    finalize_scales<<<1, 256, 0, stream>>>(part1, part2, sc);
    quant_w<<<4096, 256, 0, stream>>>((const float4*)w1, (char4*)qw1, sc, 0);
    quant_w<<<4096, 256, 0, stream>>>((const float4*)w2, (char4*)qw2, sc, 2);
    quant_x_kernel<<<NTOK, 256, 0, stream>>>(x, qx, dqx);

    dim3 g1(DH / 128, NTOK / 128);  // (32, 64)
    gemm_i8<<<g1, 256, 0, stream>>>(qx, qw1, h, dqx, sc, 1, DH, DM);

    conv_silu_quant<<<NTOK, 256, 0, stream>>>(h, cw, cb, qh, dqh);

    dim3 g2(DM / 128, NTOK / 128);  // (8, 64)
    gemm_i8<<<g2, 256, 0, stream>>>(qh, qw2, out, dqh, sc, 3, DM, DH);
}

// Round 2
// 308.888 us; speedup vs baseline: 1.0650x; 1.0650x over previous
//
#include <hip/hip_runtime.h>
#include <cstdint>

// Problem sizes (fixed by reference)
#define S_    2048
#define DM    1024
#define DH    4096
#define NTOK  8192     // B*S = 4*2048
#define WELEM 4194304  // 4096*1024 elements in each weight matrix

typedef int v4i __attribute__((ext_vector_type(4)));

// async global->LDS, 16B per lane, dest = ldsbase + lane*16 (wave-uniform base)
#define GLOAD_LDS16(g, l)                                                   \
    __builtin_amdgcn_global_load_lds(                                       \
        (const __attribute__((address_space(1))) void*)(g),                 \
        (__attribute__((address_space(3))) void*)(l), 16, 0, 0)

// ---------------------------------------------------------------------------
// Stage 1: per-block partial sums of |w| in fp64 (deterministic fixed mapping)
// 1024 blocks x 4096 elements each, float4 loads.
__global__ __launch_bounds__(256) void absmean_partial(const float4* __restrict__ w,
                                                       double* __restrict__ partial) {
    __shared__ double red[256];
    int base = blockIdx.x * 1024;  // in float4 units
    double s = 0.0;
#pragma unroll
    for (int k = 0; k < 4; ++k) {
        float4 v = w[base + (k << 8) + threadIdx.x];
        s += (double)fabsf(v.x) + (double)fabsf(v.y) +
             (double)fabsf(v.z) + (double)fabsf(v.w);
    }
    red[threadIdx.x] = s;
    __syncthreads();
    for (int off = 128; off > 0; off >>= 1) {
        if (threadIdx.x < off) red[threadIdx.x] += red[threadIdx.x + off];
        __syncthreads();
    }
    if (threadIdx.x == 0) partial[blockIdx.x] = red[0];
}

// Stage 2: deterministic tree-sum of the 1024 partials for each matrix,
// scale = 1/clip(mean,1e-5) (fp32 like reference), plus dequant = 1/scale.
__global__ __launch_bounds__(256) void finalize_scales(const double* __restrict__ p1,
                                                       const double* __restrict__ p2,
                                                       float* __restrict__ sc) {
    __shared__ double red[1024];
#pragma unroll 1
    for (int m = 0; m < 2; ++m) {
        const double* p = (m == 0) ? p1 : p2;
        __syncthreads();
#pragma unroll
        for (int k = 0; k < 4; ++k) red[(k << 8) + threadIdx.x] = p[(k << 8) + threadIdx.x];
        __syncthreads();
        double s = red[threadIdx.x] + red[threadIdx.x + 256] +
                   red[threadIdx.x + 512] + red[threadIdx.x + 768];
        __syncthreads();
        red[threadIdx.x] = s;
        __syncthreads();
        for (int off = 128; off > 0; off >>= 1) {
            if (threadIdx.x < off) red[threadIdx.x] += red[threadIdx.x + off];
            __syncthreads();
        }
        if (threadIdx.x == 0) {
            double mean = red[0] / (double)WELEM;
            float mf = fmaxf((float)mean, 1e-5f);
            float scale = 1.0f / mf;
            sc[2 * m]     = scale;
            sc[2 * m + 1] = 1.0f / scale;
        }
    }
}

// Ternary-quantize a weight matrix: q = clip(rint(w*scale), -1, 1)
__global__ __launch_bounds__(256) void quant_w(const float4* __restrict__ w,
                                               char4* __restrict__ q,
                                               const float* __restrict__ sc, int slot) {
    float scale = sc[slot];
    int i = blockIdx.x * 256 + threadIdx.x;
    float4 v = w[i];
    char4 o;
    o.x = (signed char)(int)fminf(fmaxf(rintf(v.x * scale), -1.f), 1.f);
    o.y = (signed char)(int)fminf(fmaxf(rintf(v.y * scale), -1.f), 1.f);
    o.z = (signed char)(int)fminf(fmaxf(rintf(v.z * scale), -1.f), 1.f);
    o.w = (signed char)(int)fminf(fmaxf(rintf(v.w * scale), -1.f), 1.f);
    q[i] = o;
}

// Per-token int8 absmax quantization of x (row length DM=1024), float4 loads
__global__ __launch_bounds__(256) void quant_x_kernel(const float4* __restrict__ x,
                                                      char4* __restrict__ q,
                                                      float* __restrict__ dq) {
    __shared__ float red[256];
    int t = blockIdx.x;
    float4 v = x[(size_t)t * 256 + threadIdx.x];
    float mx = fmaxf(fmaxf(fabsf(v.x), fabsf(v.y)), fmaxf(fabsf(v.z), fabsf(v.w)));
    red[threadIdx.x] = mx;
    __syncthreads();
    for (int off = 128; off > 0; off >>= 1) {
        if (threadIdx.x < off) red[threadIdx.x] = fmaxf(red[threadIdx.x], red[threadIdx.x + off]);
        __syncthreads();
    }
    float scale = 127.0f / fmaxf(red[0], 1e-5f);
    char4 o;
    o.x = (signed char)(int)fminf(fmaxf(rintf(v.x * scale), -128.f), 127.f);
    o.y = (signed char)(int)fminf(fmaxf(rintf(v.y * scale), -128.f), 127.f);
    o.z = (signed char)(int)fminf(fmaxf(rintf(v.z * scale), -128.f), 127.f);
    o.w = (signed char)(int)fminf(fmaxf(rintf(v.w * scale), -128.f), 127.f);
    q[(size_t)t * 256 + threadIdx.x] = o;
    if (threadIdx.x == 0) dq[t] = 1.0f / scale;
}

// Fused depthwise conv3 (+bias) + SiLU + per-token int8 quant over DH=4096.
// One block per token, float4 vector loads; conv weights [C][3] read as 3
// float4 per 4-channel group.
__global__ __launch_bounds__(256) void conv_silu_quant(const float4* __restrict__ h,
                                                       const float4* __restrict__ cw,
                                                       const float4* __restrict__ cb,
                                                       char4* __restrict__ q,
                                                       float* __restrict__ dq) {
    __shared__ float red[256];
    int t = blockIdx.x;
    int s = t & (S_ - 1);
    const float4* h0 = h + (size_t)t * 1024;   // 4096 floats = 1024 float4
    const float4* hm = h0 - 1024;
    const float4* hp = h0 + 1024;
    bool has_m = (s > 0), has_p = (s < S_ - 1);
    float4 v[4];
    float mx = 0.f;
#pragma unroll
    for (int k = 0; k < 4; ++k) {
        int g = (k << 8) + threadIdx.x;        // channel-group (4 channels)
        float4 a  = has_m ? hm[g] : float4{0.f, 0.f, 0.f, 0.f};
        float4 b  = h0[g];
        float4 c  = has_p ? hp[g] : float4{0.f, 0.f, 0.f, 0.f};
        float4 w0 = cw[3 * g], w1 = cw[3 * g + 1], w2 = cw[3 * g + 2];
        float4 bb = cb[g];
        float4 y;
        y.x = w0.x * a.x + w0.y * b.x + w0.z * c.x + bb.x;
        y.y = w0.w * a.y + w1.x * b.y + w1.y * c.y + bb.y;
        y.z = w1.z * a.z + w1.w * b.z + w2.x * c.z + bb.z;
        y.w = w2.y * a.w + w2.z * b.w + w2.w * c.w + bb.w;
        float4 r;
        r.x = y.x / (1.0f + expf(-y.x));
        r.y = y.y / (1.0f + expf(-y.y));
        r.z = y.z / (1.0f + expf(-y.z));
        r.w = y.w / (1.0f + expf(-y.w));
        v[k] = r;
        mx = fmaxf(mx, fmaxf(fmaxf(fabsf(r.x), fabsf(r.y)), fmaxf(fabsf(r.z), fabsf(r.w))));
    }
    red[threadIdx.x] = mx;
    __syncthreads();
    for (int off = 128; off > 0; off >>= 1) {
        if (threadIdx.x < off) red[threadIdx.x] = fmaxf(red[threadIdx.x], red[threadIdx.x + off]);
        __syncthreads();
    }
    float scale = 127.0f / fmaxf(red[0], 1e-5f);
#pragma unroll
    for (int k = 0; k < 4; ++k) {
        int g = (k << 8) + threadIdx.x;
        char4 o;
        o.x = (signed char)(int)fminf(fmaxf(rintf(v[k].x * scale), -128.f), 127.f);
        o.y = (signed char)(int)fminf(fmaxf(rintf(v[k].y * scale), -128.f), 127.f);
        o.z = (signed char)(int)fminf(fmaxf(rintf(v[k].z * scale), -128.f), 127.f);
        o.w = (signed char)(int)fminf(fmaxf(rintf(v[k].w * scale), -128.f), 127.f);
        q[(size_t)t * 1024 + g] = o;
    }
    if (threadIdx.x == 0) dq[t] = 1.0f / scale;
}

// int8 x ternary GEMM: C[m,n] = (sum_k A[m,k]*B[n,k]) * rowdq[m] * sc[slot]
// A: [M,K] int8 row-major, B: [N,K] int8 row-major (both K-contiguous).
// Block tile 128x128, 4 waves 2x2, wave tile 64x64 via 4x4 mfma_i32_16x16x64_i8.
//
// Staging via global_load_lds (16B/lane, dest forced to ldsbase + lane*16):
// wave w stages 16-row tiles {2w, 2w+1} of A and B. Within a tile, lane l
// fetches global chunk c = ((l&3) - ((l>>3)&3)) & 3 of row r = l>>2 (a
// permutation within each 64B row -> coalescing preserved). Resulting LDS
// layout: chunk(r,c) at 16*(4r + ((c + (r>>1)) & 3)).
// Fragment read: lane l (m=l&15, q=l>>4) reads chunk 4m + ((q+(m>>1))&3);
// per 16-lane phase each bank-group is hit exactly 2x (2-way = free, m136).
__global__ __launch_bounds__(256) void gemm_i8(const int8_t* __restrict__ A,
                                               const int8_t* __restrict__ Bm,
                                               float* __restrict__ C,
                                               const float* __restrict__ rowdq,
                                               const float* __restrict__ sc, int slot,
                                               int N, int K) {
    __shared__ __align__(16) int8_t Alds[8192];
    __shared__ __align__(16) int8_t Blds[8192];
    const int tid  = threadIdx.x;
    const int lane = tid & 63;
    const int wave = tid >> 6;
    const int mbase = blockIdx.y << 7;
    const int nbase = blockIdx.x << 7;
    const int wm4 = (wave >> 1) << 2;  // wave's first m-tile (16 rows each)
    const int wn4 = (wave & 1) << 2;   // wave's first n-tile

    // staging addresses
    const int r_l = lane >> 2;
    const int c_l = ((lane & 3) - ((lane >> 3) & 3)) & 3;
    const int t0 = wave * 2, t1 = t0 + 1;
    const int8_t* Ag0 = A  + (size_t)(mbase + t0 * 16 + r_l) * K + c_l * 16;
    const int8_t* Ag1 = A  + (size_t)(mbase + t1 * 16 + r_l) * K + c_l * 16;
    const int8_t* Bg0 = Bm + (size_t)(nbase + t0 * 16 + r_l) * K + c_l * 16;
    const int8_t* Bg1 = Bm + (size_t)(nbase + t1 * 16 + r_l) * K + c_l * 16;
    int8_t* Al0 = Alds + (t0 << 10);
    int8_t* Al1 = Alds + (t1 << 10);
    int8_t* Bl0 = Blds + (t0 << 10);
    int8_t* Bl1 = Blds + (t1 << 10);

    // fragment-read offset within a 1KB 16-row tile
    const int m_l = lane & 15, q_l = lane >> 4;
    const int fro = (4 * m_l + ((q_l + (m_l >> 1)) & 3)) << 4;
    const int8_t* Afr = Alds + fro;
    const int8_t* Bfr = Blds + fro;

    v4i acc[4][4] = {};

    for (int k0 = 0; k0 < K; k0 += 64) {
        __syncthreads();  // previous tile fully consumed
        GLOAD_LDS16(Ag0 + k0, Al0);
        GLOAD_LDS16(Ag1 + k0, Al1);
        GLOAD_LDS16(Bg0 + k0, Bl0);
        GLOAD_LDS16(Bg1 + k0, Bl1);
        __syncthreads();  // compiler drains vmcnt(0) before s_barrier
        v4i af[4], bf[4];
#pragma unroll
        for (int i = 0; i < 4; ++i)
            af[i] = *reinterpret_cast<const v4i*>(Afr + ((wm4 + i) << 10));
#pragma unroll
        for (int j = 0; j < 4; ++j)
            bf[j] = *reinterpret_cast<const v4i*>(Bfr + ((wn4 + j) << 10));
#pragma unroll
        for (int i = 0; i < 4; ++i)
#pragma unroll
            for (int j = 0; j < 4; ++j)
                acc[i][j] = __builtin_amdgcn_mfma_i32_16x16x64_i8(af[i], bf[j], acc[i][j], 0, 0, 0);
    }

    const float wdq = sc[slot];
    const int quad = lane >> 4;
    const int col  = lane & 15;
#pragma unroll
    for (int i = 0; i < 4; ++i) {
#pragma unroll
        for (int r = 0; r < 4; ++r) {
            int m = mbase + ((wm4 + i) << 4) + (quad << 2) + r;  // C/D: row=(lane>>4)*4+reg
            float rs = rowdq[m] * wdq;
#pragma unroll
            for (int j = 0; j < 4; ++j) {
                int n = nbase + ((wn4 + j) << 4) + col;          // C/D: col=lane&15
                C[(size_t)m * N + n] = (float)acc[i][j][r] * rs;
            }
        }
    }
}

// ---------------------------------------------------------------------------
extern "C" void kernel_launch(void* const* d_in, const int* in_sizes, int n_in,
                              void* d_out, int out_size, void* d_ws, size_t ws_size,
                              hipStream_t stream) {
    const float* x  = (const float*)d_in[0];  // [4,2048,1024]
    const float* w1 = (const float*)d_in[1];  // [4096,1024]
    const float* cw = (const float*)d_in[2];  // [4096,1,3]
    const float* cb = (const float*)d_in[3];  // [4096]
    const float* w2 = (const float*)d_in[4];  // [1024,4096]
    float* out = (float*)d_out;               // [4,2048,1024]
    char* ws = (char*)d_ws;

    // Workspace layout (16B-aligned); total ~185 MB
    double* part1 = (double*)(ws + 0);          // 1024 doubles
    double* part2 = (double*)(ws + 8192);       // 1024 doubles
    float*  sc    = (float*)(ws + 16384);       // {scale_w1, dq_w1, scale_w2, dq_w2}
    float*  dqx   = (float*)(ws + 16640);       // 8192 floats
    float*  dqh   = (float*)(ws + 49408);       // 8192 floats
    int8_t* qw1   = (int8_t*)(ws + 82176);      // 4 MB
    int8_t* qw2   = (int8_t*)(ws + 4276480);    // 4 MB
    int8_t* qx    = (int8_t*)(ws + 8470784);    // 8 MB
    int8_t* qh    = (int8_t*)(ws + 16859392);   // 32 MB
    float*  h     = (float*)(ws + 50413824);    // 128 MB

    absmean_partial<<<1024, 256, 0, stream>>>((const float4*)w1, part1);
    absmean_partial<<<1024, 256, 0, stream>>>((const float4*)w2, part2);
    finalize_scales<<<1, 256, 0, stream>>>(part1, part2, sc);
    quant_w<<<4096, 256, 0, stream>>>((const float4*)w1, (char4*)qw1, sc, 0);
    quant_w<<<4096, 256, 0, stream>>>((const float4*)w2, (char4*)qw2, sc, 2);
    quant_x_kernel<<<NTOK, 256, 0, stream>>>((const float4*)x, (char4*)qx, dqx);

    dim3 g1(DH / 128, NTOK / 128);  // (32, 64)
    gemm_i8<<<g1, 256, 0, stream>>>(qx, qw1, h, dqx, sc, 1, DH, DM);

    conv_silu_quant<<<NTOK, 256, 0, stream>>>((const float4*)h, (const float4*)cw,
                                              (const float4*)cb, (char4*)qh, dqh);

    dim3 g2(DM / 128, NTOK / 128);  // (8, 64)
    gemm_i8<<<g2, 256, 0, stream>>>(qh, qw2, out, dqh, sc, 3, DM, DH);
}

// Round 3
// 286.873 us; speedup vs baseline: 1.1467x; 1.0767x over previous
//
#include <hip/hip_runtime.h>
#include <cstdint>

// Problem sizes (fixed by reference)
#define S_    2048
#define DM    1024
#define DH    4096
#define NTOK  8192     // B*S = 4*2048
#define WELEM 4194304  // 4096*1024 elements in each weight matrix
#define CONV_T 8       // tokens per conv block

typedef int v4i __attribute__((ext_vector_type(4)));

// async global->LDS, 16B per lane, dest = ldsbase + lane*16 (wave-uniform base)
#define GLOAD_LDS16(g, l)                                                   \
    __builtin_amdgcn_global_load_lds(                                       \
        (const __attribute__((address_space(1))) void*)(g),                 \
        (__attribute__((address_space(3))) void*)(l), 16, 0, 0)

// ---------------------------------------------------------------------------
// Stage 1: per-block partial sums of |w| in fp64 (deterministic fixed mapping)
__global__ __launch_bounds__(256) void absmean_partial(const float4* __restrict__ w,
                                                       double* __restrict__ partial) {
    __shared__ double red[256];
    int base = blockIdx.x * 1024;  // in float4 units
    double s = 0.0;
#pragma unroll
    for (int k = 0; k < 4; ++k) {
        float4 v = w[base + (k << 8) + threadIdx.x];
        s += (double)fabsf(v.x) + (double)fabsf(v.y) +
             (double)fabsf(v.z) + (double)fabsf(v.w);
    }
    red[threadIdx.x] = s;
    __syncthreads();
    for (int off = 128; off > 0; off >>= 1) {
        if (threadIdx.x < off) red[threadIdx.x] += red[threadIdx.x + off];
        __syncthreads();
    }
    if (threadIdx.x == 0) partial[blockIdx.x] = red[0];
}

// Stage 2: deterministic tree-sum of partials; scale = 1/clip(mean,1e-5) fp32.
__global__ __launch_bounds__(256) void finalize_scales(const double* __restrict__ p1,
                                                       const double* __restrict__ p2,
                                                       float* __restrict__ sc) {
    __shared__ double red[1024];
#pragma unroll 1
    for (int m = 0; m < 2; ++m) {
        const double* p = (m == 0) ? p1 : p2;
        __syncthreads();
#pragma unroll
        for (int k = 0; k < 4; ++k) red[(k << 8) + threadIdx.x] = p[(k << 8) + threadIdx.x];
        __syncthreads();
        double s = red[threadIdx.x] + red[threadIdx.x + 256] +
                   red[threadIdx.x + 512] + red[threadIdx.x + 768];
        __syncthreads();
        red[threadIdx.x] = s;
        __syncthreads();
        for (int off = 128; off > 0; off >>= 1) {
            if (threadIdx.x < off) red[threadIdx.x] += red[threadIdx.x + off];
            __syncthreads();
        }
        if (threadIdx.x == 0) {
            double mean = red[0] / (double)WELEM;
            float mf = fmaxf((float)mean, 1e-5f);
            float scale = 1.0f / mf;
            sc[2 * m]     = scale;
            sc[2 * m + 1] = 1.0f / scale;
        }
    }
}

// Ternary-quantize a weight matrix: q = clip(rint(w*scale), -1, 1)
__global__ __launch_bounds__(256) void quant_w(const float4* __restrict__ w,
                                               char4* __restrict__ q,
                                               const float* __restrict__ sc, int slot) {
    float scale = sc[slot];
    int i = blockIdx.x * 256 + threadIdx.x;
    float4 v = w[i];
    char4 o;
    o.x = (signed char)(int)fminf(fmaxf(rintf(v.x * scale), -1.f), 1.f);
    o.y = (signed char)(int)fminf(fmaxf(rintf(v.y * scale), -1.f), 1.f);
    o.z = (signed char)(int)fminf(fmaxf(rintf(v.z * scale), -1.f), 1.f);
    o.w = (signed char)(int)fminf(fmaxf(rintf(v.w * scale), -1.f), 1.f);
    q[i] = o;
}

// Per-token int8 absmax quantization of x (row length DM=1024), float4 loads
__global__ __launch_bounds__(256) void quant_x_kernel(const float4* __restrict__ x,
                                                      char4* __restrict__ q,
                                                      float* __restrict__ dq) {
    __shared__ float red[256];
    int t = blockIdx.x;
    float4 v = x[(size_t)t * 256 + threadIdx.x];
    float mx = fmaxf(fmaxf(fabsf(v.x), fabsf(v.y)), fmaxf(fabsf(v.z), fabsf(v.w)));
    red[threadIdx.x] = mx;
    __syncthreads();
    for (int off = 128; off > 0; off >>= 1) {
        if (threadIdx.x < off) red[threadIdx.x] = fmaxf(red[threadIdx.x], red[threadIdx.x + off]);
        __syncthreads();
    }
    float scale = 127.0f / fmaxf(red[0], 1e-5f);
    char4 o;
    o.x = (signed char)(int)fminf(fmaxf(rintf(v.x * scale), -128.f), 127.f);
    o.y = (signed char)(int)fminf(fmaxf(rintf(v.y * scale), -128.f), 127.f);
    o.z = (signed char)(int)fminf(fmaxf(rintf(v.z * scale), -128.f), 127.f);
    o.w = (signed char)(int)fminf(fmaxf(rintf(v.w * scale), -128.f), 127.f);
    q[(size_t)t * 256 + threadIdx.x] = o;
    if (threadIdx.x == 0) dq[t] = 1.0f / scale;
}

// Fused depthwise conv3 (+bias) + SiLU + per-token int8 quant over DH=4096.
// t-tiled: one block handles CONV_T tokens with a 3-row LDS ring, so each h
// row is fetched from HBM once (+2 halo rows per block) instead of 3x.
// Conv weights/bias live in registers across the whole block.
__global__ __launch_bounds__(256) void conv_silu_quant(const float4* __restrict__ h,
                                                       const float4* __restrict__ cw,
                                                       const float4* __restrict__ cb,
                                                       char4* __restrict__ q,
                                                       float* __restrict__ dq) {
    __shared__ float4 ring[3][1024];   // 3 rows x 4096 floats = 48 KB
    __shared__ float red[4];
    const int tid = threadIdx.x;
    const int t0 = blockIdx.x * CONV_T;
    const int s0 = t0 & (S_ - 1);      // CONV_T | S_, so block never straddles batches

    // per-thread conv weights for channel-groups g = tid + k*256
    float4 w0[4], w1[4], w2[4], bb[4];
#pragma unroll
    for (int k = 0; k < 4; ++k) {
        int g = (k << 8) + tid;
        w0[k] = cw[3 * g]; w1[k] = cw[3 * g + 1]; w2[k] = cw[3 * g + 2];
        bb[k] = cb[g];
    }

    const float4 zero4 = {0.f, 0.f, 0.f, 0.f};
    // prologue: ring[0] = row t0-1 (zeros at sequence start), ring[1] = row t0
#pragma unroll
    for (int k = 0; k < 4; ++k) {
        int g = (k << 8) + tid;
        ring[0][g] = (s0 > 0) ? h[(size_t)(t0 - 1) * 1024 + g] : zero4;
        ring[1][g] = h[(size_t)t0 * 1024 + g];
    }

#pragma unroll
    for (int i = 0; i < CONV_T; ++i) {
        const int pr = i % 3, ce = (i + 1) % 3, nx = (i + 2) % 3;
        const int t = t0 + i;
        // stage row t+1 (zeros past end of sequence)
        bool has_p = (s0 + i + 1) < S_;
#pragma unroll
        for (int k = 0; k < 4; ++k) {
            int g = (k << 8) + tid;
            ring[nx][g] = has_p ? h[(size_t)(t + 1) * 1024 + g] : zero4;
        }
        __syncthreads();  // ring[nx] visible (and prologue writes on i==0)

        float4 v[4];
        float mx = 0.f;
#pragma unroll
        for (int k = 0; k < 4; ++k) {
            int g = (k << 8) + tid;
            float4 a = ring[pr][g], b = ring[ce][g], c = ring[nx][g];
            float4 y;
            y.x = w0[k].x * a.x + w0[k].y * b.x + w0[k].z * c.x + bb[k].x;
            y.y = w0[k].w * a.y + w1[k].x * b.y + w1[k].y * c.y + bb[k].y;
            y.z = w1[k].z * a.z + w1[k].w * b.z + w2[k].x * c.z + bb[k].z;
            y.w = w2[k].y * a.w + w2[k].z * b.w + w2[k].w * c.w + bb[k].w;
            float4 r;
            r.x = y.x / (1.0f + expf(-y.x));
            r.y = y.y / (1.0f + expf(-y.y));
            r.z = y.z / (1.0f + expf(-y.z));
            r.w = y.w / (1.0f + expf(-y.w));
            v[k] = r;
            mx = fmaxf(mx, fmaxf(fmaxf(fabsf(r.x), fabsf(r.y)), fmaxf(fabsf(r.z), fabsf(r.w))));
        }
        // wave shuffle reduce (width 64), then 4-wave combine via LDS
#pragma unroll
        for (int off = 32; off > 0; off >>= 1)
            mx = fmaxf(mx, __shfl_down(mx, off, 64));
        if ((tid & 63) == 0) red[tid >> 6] = mx;
        __syncthreads();  // red visible; also protects ring reads before next overwrite
        float rowmax = fmaxf(fmaxf(red[0], red[1]), fmaxf(red[2], red[3]));
        float scale = 127.0f / fmaxf(rowmax, 1e-5f);
#pragma unroll
        for (int k = 0; k < 4; ++k) {
            int g = (k << 8) + tid;
            char4 o;
            o.x = (signed char)(int)fminf(fmaxf(rintf(v[k].x * scale), -128.f), 127.f);
            o.y = (signed char)(int)fminf(fmaxf(rintf(v[k].y * scale), -128.f), 127.f);
            o.z = (signed char)(int)fminf(fmaxf(rintf(v[k].z * scale), -128.f), 127.f);
            o.w = (signed char)(int)fminf(fmaxf(rintf(v[k].w * scale), -128.f), 127.f);
            q[(size_t)t * 1024 + g] = o;
        }
        if (tid == 0) dq[t] = 1.0f / scale;
    }
}

// int8 x ternary GEMM: C[m,n] = (sum_k A[m,k]*B[n,k]) * rowdq[m] * sc[slot]
// Block tile 128x128, 4 waves 2x2, wave tile 64x64 via 4x4 mfma_i32_16x16x64_i8.
// Double-buffered global_load_lds staging with ONE barrier per K-iter:
//   barrier; prefetch tile k+1 into buf[nxt]; compute tile k from buf[cur].
// The barrier's vmcnt(0) drain then only waits on loads that have had a full
// compute phase in flight. Global-side chunk swizzle keeps fragment ds_reads
// 2-way-or-less on banks (free, m136); staging stays fully coalesced.
__global__ __launch_bounds__(256) void gemm_i8(const int8_t* __restrict__ A,
                                               const int8_t* __restrict__ Bm,
                                               float* __restrict__ C,
                                               const float* __restrict__ rowdq,
                                               const float* __restrict__ sc, int slot,
                                               int N, int K) {
    __shared__ __align__(16) int8_t Alds[2][8192];
    __shared__ __align__(16) int8_t Blds[2][8192];
    const int tid  = threadIdx.x;
    const int lane = tid & 63;
    const int wave = tid >> 6;
    const int mbase = blockIdx.y << 7;
    const int nbase = blockIdx.x << 7;
    const int wm4 = (wave >> 1) << 2;
    const int wn4 = (wave & 1) << 2;

    // staging addresses: lane l -> row r_l = l>>2, swizzled chunk c_l
    const int r_l = lane >> 2;
    const int c_l = ((lane & 3) - ((lane >> 3) & 3)) & 3;
    const int t0 = wave * 2, t1 = t0 + 1;
    const int8_t* Ag0 = A  + (size_t)(mbase + t0 * 16 + r_l) * K + c_l * 16;
    const int8_t* Ag1 = A  + (size_t)(mbase + t1 * 16 + r_l) * K + c_l * 16;
    const int8_t* Bg0 = Bm + (size_t)(nbase + t0 * 16 + r_l) * K + c_l * 16;
    const int8_t* Bg1 = Bm + (size_t)(nbase + t1 * 16 + r_l) * K + c_l * 16;
    const int lt0 = t0 << 10, lt1 = t1 << 10;

    // fragment-read offset within a 1KB 16-row tile
    const int m_l = lane & 15, q_l = lane >> 4;
    const int fro = (4 * m_l + ((q_l + (m_l >> 1)) & 3)) << 4;

    v4i acc[4][4] = {};

    // prologue: prefetch k=0 into buffer 0
    GLOAD_LDS16(Ag0, &Alds[0][lt0]);
    GLOAD_LDS16(Ag1, &Alds[0][lt1]);
    GLOAD_LDS16(Bg0, &Blds[0][lt0]);
    GLOAD_LDS16(Bg1, &Blds[0][lt1]);

    const int niter = K >> 6;

#define GEMM_STEP(CUR, NXT, IT)                                              \
    {                                                                        \
        __syncthreads();                                                     \
        if ((IT) + 1 < niter) {                                              \
            const int ko = ((IT) + 1) << 6;                                  \
            GLOAD_LDS16(Ag0 + ko, &Alds[NXT][lt0]);                          \
            GLOAD_LDS16(Ag1 + ko, &Alds[NXT][lt1]);                          \
            GLOAD_LDS16(Bg0 + ko, &Blds[NXT][lt0]);                          \
            GLOAD_LDS16(Bg1 + ko, &Blds[NXT][lt1]);                          \
        }                                                                    \
        v4i af[4], bf[4];                                                    \
        _Pragma("unroll")                                                    \
        for (int i = 0; i < 4; ++i)                                          \
            af[i] = *reinterpret_cast<const v4i*>(&Alds[CUR][fro + ((wm4 + i) << 10)]); \
        _Pragma("unroll")                                                    \
        for (int j = 0; j < 4; ++j)                                          \
            bf[j] = *reinterpret_cast<const v4i*>(&Blds[CUR][fro + ((wn4 + j) << 10)]); \
        _Pragma("unroll")                                                    \
        for (int i = 0; i < 4; ++i)                                          \
            _Pragma("unroll")                                                \
            for (int j = 0; j < 4; ++j)                                      \
                acc[i][j] = __builtin_amdgcn_mfma_i32_16x16x64_i8(af[i], bf[j], acc[i][j], 0, 0, 0); \
    }

    // niter is even (16 or 64) -> unroll by 2 keeps buffer index compile-time
    for (int it = 0; it < niter; it += 2) {
        GEMM_STEP(0, 1, it);
        GEMM_STEP(1, 0, it + 1);
    }
#undef GEMM_STEP

    const float wdq = sc[slot];
    const int quad = lane >> 4;
    const int col  = lane & 15;
#pragma unroll
    for (int i = 0; i < 4; ++i) {
#pragma unroll
        for (int r = 0; r < 4; ++r) {
            int m = mbase + ((wm4 + i) << 4) + (quad << 2) + r;  // C/D: row=(lane>>4)*4+reg
            float rs = rowdq[m] * wdq;
#pragma unroll
            for (int j = 0; j < 4; ++j) {
                int n = nbase + ((wn4 + j) << 4) + col;          // C/D: col=lane&15
                C[(size_t)m * N + n] = (float)acc[i][j][r] * rs;
            }
        }
    }
}

// ---------------------------------------------------------------------------
extern "C" void kernel_launch(void* const* d_in, const int* in_sizes, int n_in,
                              void* d_out, int out_size, void* d_ws, size_t ws_size,
                              hipStream_t stream) {
    const float* x  = (const float*)d_in[0];  // [4,2048,1024]
    const float* w1 = (const float*)d_in[1];  // [4096,1024]
    const float* cw = (const float*)d_in[2];  // [4096,1,3]
    const float* cb = (const float*)d_in[3];  // [4096]
    const float* w2 = (const float*)d_in[4];  // [1024,4096]
    float* out = (float*)d_out;               // [4,2048,1024]
    char* ws = (char*)d_ws;

    // Workspace layout (16B-aligned); total ~185 MB
    double* part1 = (double*)(ws + 0);          // 1024 doubles
    double* part2 = (double*)(ws + 8192);       // 1024 doubles
    float*  sc    = (float*)(ws + 16384);       // {scale_w1, dq_w1, scale_w2, dq_w2}
    float*  dqx   = (float*)(ws + 16640);       // 8192 floats
    float*  dqh   = (float*)(ws + 49408);       // 8192 floats
    int8_t* qw1   = (int8_t*)(ws + 82176);      // 4 MB
    int8_t* qw2   = (int8_t*)(ws + 4276480);    // 4 MB
    int8_t* qx    = (int8_t*)(ws + 8470784);    // 8 MB
    int8_t* qh    = (int8_t*)(ws + 16859392);   // 32 MB
    float*  h     = (float*)(ws + 50413824);    // 128 MB

    absmean_partial<<<1024, 256, 0, stream>>>((const float4*)w1, part1);
    absmean_partial<<<1024, 256, 0, stream>>>((const float4*)w2, part2);
    finalize_scales<<<1, 256, 0, stream>>>(part1, part2, sc);
    quant_w<<<4096, 256, 0, stream>>>((const float4*)w1, (char4*)qw1, sc, 0);
    quant_w<<<4096, 256, 0, stream>>>((const float4*)w2, (char4*)qw2, sc, 2);
    quant_x_kernel<<<NTOK, 256, 0, stream>>>((const float4*)x, (char4*)qx, dqx);

    dim3 g1(DH / 128, NTOK / 128);  // (32, 64)
    gemm_i8<<<g1, 256, 0, stream>>>(qx, qw1, h, dqx, sc, 1, DH, DM);

    conv_silu_quant<<<NTOK / CONV_T, 256, 0, stream>>>((const float4*)h, (const float4*)cw,
                                                       (const float4*)cb, (char4*)qh, dqh);

    dim3 g2(DM / 128, NTOK / 128);  // (8, 64)
    gemm_i8<<<g2, 256, 0, stream>>>(qh, qw2, out, dqh, sc, 3, DM, DH);
}